// Round 11
// baseline (566.828 us; speedup 1.0000x reference)
//
#include <hip/hip_runtime.h>

typedef __attribute__((ext_vector_type(4))) float f32x4;
typedef __attribute__((ext_vector_type(8))) short bf16x8;
typedef __attribute__((ext_vector_type(4))) unsigned short u16x4;
typedef unsigned short u16;

#define HW 3136
#define NSEG 49
#define NELF 802816.0f
#define EPS 1e-5f

__device__ __forceinline__ short f2bf(float f) {
  union { float f; unsigned u; } v; v.f = f;
  unsigned r = (v.u + 0x7FFFu + ((v.u >> 16) & 1u)) >> 16;
  return (short)r;
}
__device__ __forceinline__ float b2f(u16 u) {
  union { unsigned u; float f; } v; v.u = ((unsigned)u) << 16;
  return v.f;
}
__device__ __forceinline__ float fgelu(float x) {
  float x2 = x * x;
  float u = x * (0.7978845608f + 0.0356774081f * x2);
  float e = __expf(-2.0f * u);
  return x * __builtin_amdgcn_rcpf(1.0f + e);
}
__device__ __forceinline__ void gload16(const void* g, void* l) {
  __builtin_amdgcn_global_load_lds(
      (const __attribute__((address_space(1))) void*)(uintptr_t)g,
      (__attribute__((address_space(3))) void*)(unsigned)(uintptr_t)l,
      16, 0, 0);
}
__device__ __forceinline__ float wred(float v) {
#pragma unroll
  for (int m = 32; m; m >>= 1) v += __shfl_xor(v, m, 64);
  return v;
}

// ---- W0a: fold GN column scales into weights, convert to bf16 ----
__global__ void wfold_kernel(const float* __restrict__ c1, const float* __restrict__ c21,
                             const float* __restrict__ c22, const float* __restrict__ c3,
                             const float* __restrict__ fc1, const float* __restrict__ fc2,
                             const float* __restrict__ n1w, const float* __restrict__ an2w,
                             const float* __restrict__ n2w, u16* __restrict__ out) {
  int i = (blockIdx.x * 256 + threadIdx.x) * 4;
  const float* src; int off; const float* scale = nullptr;
  if (i < 65536)       { src = c1;  off = 0;       scale = n1w; }
  else if (i < 131072) { src = c21; off = 65536; }
  else if (i < 196608) { src = c22; off = 131072; }
  else if (i < 262144) { src = c3;  off = 196608;  scale = an2w; }
  else if (i < 524288) { src = fc1; off = 262144;  scale = n2w; }
  else                 { src = fc2; off = 524288; }
  int li = i - off;
  float4 v = *(const float4*)(src + li);
  if (scale) {
    float4 g = *(const float4*)(scale + (li & 255));
    v.x *= g.x; v.y *= g.y; v.z *= g.z; v.w *= g.w;
  }
  u16x4 o4; o4[0] = (u16)f2bf(v.x); o4[1] = (u16)f2bf(v.y); o4[2] = (u16)f2bf(v.z); o4[3] = (u16)f2bf(v.w);
  *(u16x4*)(out + i) = o4;
}

// ---- W0b: Sg/Sb row sums ----
__global__ void rowsum_kernel(const float* __restrict__ c1w, const float* __restrict__ c1b,
                              const float* __restrict__ n1w, const float* __restrict__ n1b,
                              const float* __restrict__ c3w, const float* __restrict__ c3b,
                              const float* __restrict__ an2w, const float* __restrict__ an2b,
                              const float* __restrict__ fc1w, const float* __restrict__ fc1b,
                              const float* __restrict__ n2w, const float* __restrict__ n2b,
                              float* __restrict__ sums) {
  int o = blockIdx.x * 256 + threadIdx.x;
  const float *W, *gw, *gb, *cb; float *Sg, *Sb; int row;
  if (o < 256)      { W = c1w;  gw = n1w;  gb = n1b;  cb = c1b;  Sg = sums;        Sb = sums + 256;  row = o; }
  else if (o < 512) { W = c3w;  gw = an2w; gb = an2b; cb = c3b;  Sg = sums + 512;  Sb = sums + 768;  row = o - 256; }
  else              { W = fc1w; gw = n2w;  gb = n2b;  cb = fc1b; Sg = sums + 1024; Sb = sums + 2048; row = o - 512; }
  float sg = 0.f, sb = 0.f;
  for (int c = 0; c < 256; c += 4) {
    float4 w = *(const float4*)(W + (size_t)row * 256 + c);
    float4 g = *(const float4*)(gw + c);
    float4 b = *(const float4*)(gb + c);
    sg += w.x * g.x + w.y * g.y + w.z * g.z + w.w * g.w;
    sb += w.x * b.x + w.y * b.y + w.z * b.z + w.w * b.w;
  }
  Sg[row] = sg; Sb[row] = sb + cb[row];
}

// ---- T0: stats(x) + transpose x -> xT bf16 [gpix][256] ----
__global__ __launch_bounds__(256) void t0_kernel(const float* __restrict__ x,
                                                 u16* __restrict__ xT, float* __restrict__ st) {
  __shared__ __align__(16) u16 tile[64 * 256];
  const int t = threadIdx.x;
  const int n = blockIdx.x / NSEG;
  const int hw0 = (blockIdx.x % NSEG) * 64;
  const int pix = t & 63;
  float s = 0.f, q = 0.f;
#pragma unroll
  for (int r = 0; r < 16; ++r) {
    int cq = (t >> 6) + (r << 2);
    int c = cq * 4;
    u16x4 o4;
#pragma unroll
    for (int i = 0; i < 4; ++i) {
      float v = x[((size_t)n * 256 + c + i) * HW + hw0 + pix];
      s += v; q += v * v;
      o4[i] = (u16)f2bf(v);
    }
    int u = cq ^ ((pix & 15) << 2);
    *(u16x4*)((char*)tile + pix * 512 + u * 8) = o4;
  }
  __syncthreads();
  {
    const int p2 = t >> 2;
#pragma unroll
    for (int r = 0; r < 8; ++r) {
      int oct = (t & 3) + (r << 2);
      int up = (2 * oct) ^ ((p2 & 15) << 2);
      bf16x8 v = *(const bf16x8*)((char*)tile + p2 * 512 + up * 8);
      *(bf16x8*)&xT[((size_t)n * HW + hw0 + p2) * 256 + oct * 8] = v;
    }
  }
  s = wred(s); q = wred(q);
  if ((t & 63) == 0) { atomicAdd(&st[n * 2], s); atomicAdd(&st[n * 2 + 1], q); }
}

// ---- e2g: tA = shift_w(fgelu(gn_as1(y))), tB = shift_h(...), channel-last ----
__global__ void e2g_kernel(const u16* __restrict__ y, u16* __restrict__ tA, u16* __restrict__ tB,
                           const float* __restrict__ gw, const float* __restrict__ gb,
                           const float* __restrict__ stats) {
  const int NU = 16 * HW * 32;
  for (int u = blockIdx.x * blockDim.x + threadIdx.x; u < NU;
       u += gridDim.x * blockDim.x) {
    const int oct = u & 31;
    const int gpix = u >> 5;
    const int n = gpix / HW;
    const int hwg = gpix - n * HW;
    const int c0 = oct * 8;
    const int g0 = c0 / 37;
    const int s0 = 3 - g0;
    int js = (g0 + 1) * 37 - c0; if (js > 8) js = 8;
    const int wc = hwg % 56, hc = hwg / 56;
    const size_t rowb = (size_t)n * HW;

    float sm = stats[n * 2], sq = stats[n * 2 + 1];
    float mn = sm * (1.0f / NELF);
    float rstd = rsqrtf(sq * (1.0f / NELF) - mn * mn + EPS);

    int pa0 = hwg + s0;            pa0 = pa0 < 0 ? 0 : (pa0 > HW - 1 ? HW - 1 : pa0);
    int pa1 = hwg + s0 - 1;        pa1 = pa1 < 0 ? 0 : (pa1 > HW - 1 ? HW - 1 : pa1);
    int pb0 = hwg + 56 * s0;       pb0 = pb0 < 0 ? 0 : (pb0 > HW - 1 ? HW - 1 : pb0);
    int pb1 = hwg + 56 * (s0 - 1); pb1 = pb1 < 0 ? 0 : (pb1 > HW - 1 ? HW - 1 : pb1);
    bf16x8 vA0 = *(const bf16x8*)(y + (rowb + pa0) * 256 + c0);
    bf16x8 vA1 = *(const bf16x8*)(y + (rowb + pa1) * 256 + c0);
    bf16x8 vB0 = *(const bf16x8*)(y + (rowb + pb0) * 256 + c0);
    bf16x8 vB1 = *(const bf16x8*)(y + (rowb + pb1) * 256 + c0);

    const bool a0 = (unsigned)(wc + s0) < 56u, a1 = (unsigned)(wc + s0 - 1) < 56u;
    const bool b0 = (unsigned)(hc + s0) < 56u, b1 = (unsigned)(hc + s0 - 1) < 56u;
    bf16x8 oA, oB;
#pragma unroll
    for (int j = 0; j < 8; ++j) {
      const int c = c0 + j;
      const float sc = rstd * gw[c];
      const float sh = gb[c] - mn * sc;
      const bool lo = j < js;
      u16 srcA = lo ? (u16)vA0[j] : (u16)vA1[j];
      u16 srcB = lo ? (u16)vB0[j] : (u16)vB1[j];
      bool okA = lo ? a0 : a1;
      bool okB = lo ? b0 : b1;
      oA[j] = okA ? f2bf(fgelu(b2f(srcA) * sc + sh)) : (short)0;
      oB[j] = okB ? f2bf(fgelu(b2f(srcB) * sc + sh)) : (short)0;
    }
    *(bf16x8*)&tA[(size_t)gpix * 256 + c0] = oA;
    *(bf16x8*)&tB[(size_t)gpix * 256 + c0] = oB;
  }
}

// ================= sq128: m97-shaped GEMM, 128 out x 128 pix, BK=32 dbuf =================
// grid (OTOT/128, 392). XCD-locality remap: dispatch d -> xcd = d&7 owns pixel tiles
// [xcd*49, (xcd+1)*49); the OT out-tiles of one pixel tile run consecutively on one XCD.
// EPI: 0 y (fold, CL store, stats) | 1 x2 (fold + resid, CL store, stats)
//      2 hid (fold + gelu, CL store) | 3 out (bias + resid, f32 [n][c][hw] store)
#define SQ_STAGE(par, ks) do {                                          \
    gload16(srcA0 + (ks) * 32, &lds[(par) * 4096 + t * 8]);             \
    gload16(srcA1 + (ks) * 32, &lds[(par) * 4096 + 2048 + t * 8]);      \
    gload16(srcB0 + (ks) * 32, &lds[8192 + (par) * 4096 + t * 8]);      \
    gload16(srcB1 + (ks) * 32, &lds[8192 + (par) * 4096 + 2048 + t * 8]); \
  } while (0)

template<int KTOT, int OTOT, int EPI>
__global__ __launch_bounds__(256, 3) void sq128(
    const u16* __restrict__ actT, const u16* __restrict__ wt,
    const float* __restrict__ Sg, const float* __restrict__ Sb,
    const float* __restrict__ stats_in, float* __restrict__ stats_out,
    const u16* __restrict__ residCL, float* __restrict__ out_f32,
    u16* __restrict__ outCL)
{
  constexpr int NK = KTOT / 32;
  __shared__ __align__(16) u16 lds[16384];   // 32 KB: A par0/par1 [0,8192); B [8192,16384)
  const int t = threadIdx.x;
  const int lane = t & 63, wave = t >> 6;
  const int fr = lane & 15, fq = lane >> 4;
  const int wo = wave >> 1, wp = wave & 1;
  // XCD-locality remap (bijective; gridDim.y == 392 == 8*49)
  const int d = blockIdx.x + gridDim.x * blockIdx.y;
  const int OT = gridDim.x;
  const int xcd = d & 7;
  const int s_ = d >> 3;
  const int obase = (s_ % OT) * 128;
  const int gp0 = (xcd * 49 + s_ / OT) * 128;

  // staging sources (sigma-swizzle folded into per-lane global source)
  const int r0 = t >> 2, sg0 = ((t & 3) - (r0 >> 1)) & 3;
  const u16* srcA0 = wt + (size_t)(obase + r0) * KTOT + sg0 * 8;
  const u16* srcA1 = wt + (size_t)(obase + 64 + r0) * KTOT + sg0 * 8;
  const u16* srcB0 = actT + (size_t)(gp0 + r0) * KTOT + sg0 * 8;
  const u16* srcB1 = actT + (size_t)(gp0 + 64 + r0) * KTOT + sg0 * 8;

  int aU[4], bU[4];
#pragma unroll
  for (int os = 0; os < 4; ++os) { int row = wo * 64 + os * 16 + fr; aU[os] = (4 * row + ((fq + (row >> 1)) & 3)) * 8; }
#pragma unroll
  for (int ps = 0; ps < 4; ++ps) { int row = wp * 64 + ps * 16 + fr; bU[ps] = 8192 + (4 * row + ((fq + (row >> 1)) & 3)) * 8; }

  f32x4 acc[4][4];
#pragma unroll
  for (int a = 0; a < 4; ++a)
#pragma unroll
    for (int b = 0; b < 4; ++b) acc[a][b] = (f32x4){0.f, 0.f, 0.f, 0.f};

  SQ_STAGE(0, 0);
  __syncthreads();
  for (int ks = 0; ks < NK; ++ks) {
    const int par = ks & 1;
    if (ks + 1 < NK) SQ_STAGE(par ^ 1, ks + 1);
    bf16x8 afr[4], bfr[4];
#pragma unroll
    for (int os = 0; os < 4; ++os) afr[os] = *(const bf16x8*)&lds[par * 4096 + aU[os]];
#pragma unroll
    for (int ps = 0; ps < 4; ++ps) bfr[ps] = *(const bf16x8*)&lds[par * 4096 + bU[ps]];
#pragma unroll
    for (int os = 0; os < 4; ++os)
#pragma unroll
      for (int ps = 0; ps < 4; ++ps)
        acc[os][ps] = __builtin_amdgcn_mfma_f32_16x16x32_bf16(afr[os], bfr[ps], acc[os][ps], 0, 0, 0);
    __syncthreads();
  }

  // ---- sample-straddle constants ----
  const int n0 = gp0 / HW;
  const int bnd = (n0 + 1) * HW;
  const int n1 = (n0 < 15) ? n0 + 1 : n0;

  if (EPI != 3) {
    float rstd0 = 1.f, mr0 = 0.f, rstd1 = 1.f, mr1 = 0.f;
    {
      float sm = stats_in[n0 * 2], sq = stats_in[n0 * 2 + 1];
      float mn = sm * (1.0f / NELF);
      rstd0 = rsqrtf(sq * (1.0f / NELF) - mn * mn + EPS); mr0 = mn * rstd0;
      float sm1 = stats_in[n1 * 2], sq1 = stats_in[n1 * 2 + 1];
      float mn1 = sm1 * (1.0f / NELF);
      rstd1 = rsqrtf(sq1 * (1.0f / NELF) - mn1 * mn1 + EPS); mr1 = mn1 * rstd1;
    }
    char* tl = (char*)lds;
    float ls0 = 0.f, lq0 = 0.f, ls1 = 0.f, lq1 = 0.f;
#pragma unroll
    for (int os = 0; os < 4; ++os) {
      const int chl = wo * 64 + os * 16 + fq * 4;
      const int ob = obase + chl;
      float4 g4 = *(const float4*)&Sg[ob];
      float4 s4 = *(const float4*)&Sb[ob];
      float be0[4] = {s4.x - mr0 * g4.x, s4.y - mr0 * g4.y, s4.z - mr0 * g4.z, s4.w - mr0 * g4.w};
      float be1[4] = {s4.x - mr1 * g4.x, s4.y - mr1 * g4.y, s4.z - mr1 * g4.z, s4.w - mr1 * g4.w};
      const int q8 = chl >> 2;
#pragma unroll
      for (int ps = 0; ps < 4; ++ps) {
        const int lp = wp * 64 + ps * 16 + fr;
        const int gpix = gp0 + lp;
        const bool hi = (gpix >= bnd);
        const float rs = hi ? rstd1 : rstd0;
        u16x4 rv = {0, 0, 0, 0};
        if (EPI == 1) rv = *(const u16x4*)&residCL[(size_t)gpix * 256 + ob];
        u16x4 pk;
#pragma unroll
        for (int j = 0; j < 4; ++j) {
          float v = fmaf(acc[os][ps][j], rs, hi ? be1[j] : be0[j]);
          if (EPI == 1) v += b2f(rv[j]);
          if (EPI == 2) v = fgelu(v);
          if (EPI == 0 || EPI == 1) {
            if (hi) { ls1 += v; lq1 += v * v; } else { ls0 += v; lq0 += v * v; }
          }
          pk[j] = (u16)f2bf(v);
        }
        *(u16x4*)(tl + lp * 256 + ((q8 ^ ((lp & 7) << 1)) & 31) * 8) = pk;
      }
    }
    __syncthreads();
#pragma unroll
    for (int r = 0; r < 8; ++r) {
      const int idx = r * 256 + t;
      const int p = idx >> 4, o8 = idx & 15;
      bf16x8 v = *(const bf16x8*)(tl + p * 256 + (((2 * o8) ^ ((p & 7) << 1)) & 31) * 8);
      *(bf16x8*)&outCL[(size_t)(gp0 + p) * OTOT + obase + o8 * 8] = v;
    }
    if (EPI == 0 || EPI == 1) {
      ls0 = wred(ls0); lq0 = wred(lq0); ls1 = wred(ls1); lq1 = wred(lq1);
      if (lane == 0) {
        atomicAdd(&stats_out[n0 * 2], ls0); atomicAdd(&stats_out[n0 * 2 + 1], lq0);
        atomicAdd(&stats_out[n1 * 2], ls1); atomicAdd(&stats_out[n1 * 2 + 1], lq1);
      }
    }
  } else {
    // EPI 3: out = acc + bias + resid -> f32 [n][c][hw]
#pragma unroll
    for (int os = 0; os < 4; ++os) {
      const int ob = obase + wo * 64 + os * 16 + fq * 4;
      float4 b4 = *(const float4*)&Sb[ob];
      float bb[4] = {b4.x, b4.y, b4.z, b4.w};
#pragma unroll
      for (int ps = 0; ps < 4; ++ps) {
        const int gpix = gp0 + wp * 64 + ps * 16 + fr;
        const bool hi = (gpix >= bnd);
        const int n = hi ? n0 + 1 : n0;
        const int hw = gpix - n * HW;
        u16x4 rv = *(const u16x4*)&residCL[(size_t)gpix * 256 + ob];
#pragma unroll
        for (int j = 0; j < 4; ++j)
          out_f32[((size_t)n * 256 + ob + j) * HW + hw] = acc[os][ps][j] + bb[j] + b2f(rv[j]);
      }
    }
  }
}

// ================= dual8: z = fgelu(conv21(tA)) + fgelu(conv22(tB)), sq128-shaped =========
// grid (2, 392), XCD remap. 16 ksteps: 0-7 = (w21, tA) -> accA ; 8-15 = (w22, tB) -> accB.
__global__ __launch_bounds__(256, 2) void dual8(
    const u16* __restrict__ tA, const u16* __restrict__ tB,
    const u16* __restrict__ w21, const u16* __restrict__ w22,
    const float* __restrict__ b21, const float* __restrict__ b22,
    float* __restrict__ stats_out, u16* __restrict__ zT)
{
  __shared__ __align__(16) u16 lds[16384];
  const int t = threadIdx.x;
  const int lane = t & 63, wave = t >> 6;
  const int fr = lane & 15, fq = lane >> 4;
  const int wo = wave >> 1, wp = wave & 1;
  const int d = blockIdx.x + gridDim.x * blockIdx.y;
  const int OT = gridDim.x;
  const int xcd = d & 7;
  const int s_ = d >> 3;
  const int obase = (s_ % OT) * 128;
  const int gp0 = (xcd * 49 + s_ / OT) * 128;

  const int r0 = t >> 2, sg0 = ((t & 3) - (r0 >> 1)) & 3;
  const u16* a21_0 = w21 + (size_t)(obase + r0) * 256 + sg0 * 8;
  const u16* a21_1 = w21 + (size_t)(obase + 64 + r0) * 256 + sg0 * 8;
  const u16* a22_0 = w22 + (size_t)(obase + r0) * 256 + sg0 * 8;
  const u16* a22_1 = w22 + (size_t)(obase + 64 + r0) * 256 + sg0 * 8;
  const u16* bA_0 = tA + (size_t)(gp0 + r0) * 256 + sg0 * 8;
  const u16* bA_1 = tA + (size_t)(gp0 + 64 + r0) * 256 + sg0 * 8;
  const u16* bB_0 = tB + (size_t)(gp0 + r0) * 256 + sg0 * 8;
  const u16* bB_1 = tB + (size_t)(gp0 + 64 + r0) * 256 + sg0 * 8;

  int aU[4], bU[4];
#pragma unroll
  for (int os = 0; os < 4; ++os) { int row = wo * 64 + os * 16 + fr; aU[os] = (4 * row + ((fq + (row >> 1)) & 3)) * 8; }
#pragma unroll
  for (int ps = 0; ps < 4; ++ps) { int row = wp * 64 + ps * 16 + fr; bU[ps] = 8192 + (4 * row + ((fq + (row >> 1)) & 3)) * 8; }

  f32x4 accA[4][4], accB[4][4];
#pragma unroll
  for (int a = 0; a < 4; ++a)
#pragma unroll
    for (int b = 0; b < 4; ++b) { accA[a][b] = (f32x4){0, 0, 0, 0}; accB[a][b] = (f32x4){0, 0, 0, 0}; }

  gload16(a21_0, &lds[t * 8]);
  gload16(a21_1, &lds[2048 + t * 8]);
  gload16(bA_0, &lds[8192 + t * 8]);
  gload16(bA_1, &lds[8192 + 2048 + t * 8]);
  __syncthreads();

#pragma unroll
  for (int ks = 0; ks < 16; ++ks) {
    const int par = ks & 1;
    if (ks < 15) {
      const int nk = ks + 1;
      const u16 *p0, *p1, *q0, *q1; int k0;
      if (nk < 8) { k0 = nk * 32; p0 = a21_0; p1 = a21_1; q0 = bA_0; q1 = bA_1; }
      else { k0 = (nk - 8) * 32; p0 = a22_0; p1 = a22_1; q0 = bB_0; q1 = bB_1; }
      gload16(p0 + k0, &lds[(par ^ 1) * 4096 + t * 8]);
      gload16(p1 + k0, &lds[(par ^ 1) * 4096 + 2048 + t * 8]);
      gload16(q0 + k0, &lds[8192 + (par ^ 1) * 4096 + t * 8]);
      gload16(q1 + k0, &lds[8192 + (par ^ 1) * 4096 + 2048 + t * 8]);
    }
    bf16x8 afr[4], bfr[4];
#pragma unroll
    for (int os = 0; os < 4; ++os) afr[os] = *(const bf16x8*)&lds[par * 4096 + aU[os]];
#pragma unroll
    for (int ps = 0; ps < 4; ++ps) bfr[ps] = *(const bf16x8*)&lds[par * 4096 + bU[ps]];
    if (ks < 8) {
#pragma unroll
      for (int os = 0; os < 4; ++os)
#pragma unroll
        for (int ps = 0; ps < 4; ++ps)
          accA[os][ps] = __builtin_amdgcn_mfma_f32_16x16x32_bf16(afr[os], bfr[ps], accA[os][ps], 0, 0, 0);
    } else {
#pragma unroll
      for (int os = 0; os < 4; ++os)
#pragma unroll
        for (int ps = 0; ps < 4; ++ps)
          accB[os][ps] = __builtin_amdgcn_mfma_f32_16x16x32_bf16(afr[os], bfr[ps], accB[os][ps], 0, 0, 0);
    }
    __syncthreads();
  }

  // ---- epilogue: z = fgelu(accA + b21) + fgelu(accB + b22); CL store + stats ----
  const int n0 = gp0 / HW;
  const int bnd = (n0 + 1) * HW;
  const int n1 = (n0 < 15) ? n0 + 1 : n0;
  char* tl = (char*)lds;
  float ls0 = 0.f, lq0 = 0.f, ls1 = 0.f, lq1 = 0.f;
#pragma unroll
  for (int os = 0; os < 4; ++os) {
    const int chl = wo * 64 + os * 16 + fq * 4;
    const int ob = obase + chl;
    float4 a4 = *(const float4*)&b21[ob];
    float4 c4 = *(const float4*)&b22[ob];
    float ba[4] = {a4.x, a4.y, a4.z, a4.w};
    float bb[4] = {c4.x, c4.y, c4.z, c4.w};
    const int q8 = chl >> 2;
#pragma unroll
    for (int ps = 0; ps < 4; ++ps) {
      const int lp = wp * 64 + ps * 16 + fr;
      const bool hi = (gp0 + lp >= bnd);
      u16x4 pk;
#pragma unroll
      for (int j = 0; j < 4; ++j) {
        float z = fgelu(accA[os][ps][j] + ba[j]) + fgelu(accB[os][ps][j] + bb[j]);
        if (hi) { ls1 += z; lq1 += z * z; } else { ls0 += z; lq0 += z * z; }
        pk[j] = (u16)f2bf(z);
      }
      *(u16x4*)(tl + lp * 256 + ((q8 ^ ((lp & 7) << 1)) & 31) * 8) = pk;
    }
  }
  __syncthreads();
#pragma unroll
  for (int r = 0; r < 8; ++r) {
    const int idx = r * 256 + t;
    const int p = idx >> 4, o8 = idx & 15;
    bf16x8 v = *(const bf16x8*)(tl + p * 256 + (((2 * o8) ^ ((p & 7) << 1)) & 31) * 8);
    *(bf16x8*)&zT[(size_t)(gp0 + p) * 256 + obase + o8 * 8] = v;
  }
  ls0 = wred(ls0); lq0 = wred(lq0); ls1 = wred(ls1); lq1 = wred(lq1);
  if (lane == 0) {
    atomicAdd(&stats_out[n0 * 2], ls0); atomicAdd(&stats_out[n0 * 2 + 1], lq0);
    atomicAdd(&stats_out[n1 * 2], ls1); atomicAdd(&stats_out[n1 * 2 + 1], lq1);
  }
}

extern "C" void kernel_launch(void* const* d_in, const int* in_sizes, int n_in,
                              void* d_out, int out_size, void* d_ws, size_t ws_size,
                              hipStream_t stream) {
  const float* x     = (const float*)d_in[0];
  const float* n1_w  = (const float*)d_in[1];
  const float* n1_b  = (const float*)d_in[2];
  const float* c1_w  = (const float*)d_in[3];
  const float* c1_b  = (const float*)d_in[4];
  const float* an1_w = (const float*)d_in[5];
  const float* an1_b = (const float*)d_in[6];
  const float* c21_w = (const float*)d_in[7];
  const float* c21_b = (const float*)d_in[8];
  const float* c22_w = (const float*)d_in[9];
  const float* c22_b = (const float*)d_in[10];
  const float* an2_w = (const float*)d_in[11];
  const float* an2_b = (const float*)d_in[12];
  const float* c3_w  = (const float*)d_in[13];
  const float* c3_b  = (const float*)d_in[14];
  const float* n2_w  = (const float*)d_in[15];
  const float* n2_b  = (const float*)d_in[16];
  const float* fc1_w = (const float*)d_in[17];
  const float* fc1_b = (const float*)d_in[18];
  const float* fc2_w = (const float*)d_in[19];
  const float* fc2_b = (const float*)d_in[20];

  char* ws = (char*)d_ws;
  float* stats = (float*)ws;
  float* sums  = (float*)(ws + 1024);
  u16* wbuf = (u16*)(ws + 16384);
  u16* wb_c1g  = wbuf;
  u16* wb_c21  = wbuf + 65536;
  u16* wb_c22  = wbuf + 131072;
  u16* wb_c3g  = wbuf + 196608;
  u16* wb_fc1g = wbuf + 262144;
  u16* wb_fc2  = wbuf + 524288;
  const size_t AB = 25690112;
  char* A0 = ws + 1638400;
  u16* xT  = (u16*)(A0);                  // S0: t0 -> G3 resid
  u16* yT  = (u16*)(A0 + AB);             // S1: G1 -> e2g; then zT
  u16* tA  = (u16*)(A0 + 2 * AB);         // S2: e2g -> dual8
  u16* tB  = (u16*)(A0 + 3 * AB);         // S3: e2g -> dual8
  u16* zT  = (u16*)(A0 + AB);             // S1 reuse
  u16* x2T = (u16*)(A0 + 4 * AB);         // S4: G3 -> G4, G5
  u16* hid = (u16*)(A0);                  // S0..S3 overlay (102.76 MB), dead inputs by G4
  float* out = (float*)d_out;

  hipMemsetAsync(stats, 0, 512, stream);
  wfold_kernel<<<768, 256, 0, stream>>>(c1_w, c21_w, c22_w, c3_w, fc1_w, fc2_w,
                                        n1_w, an2_w, n2_w, wbuf);
  rowsum_kernel<<<6, 256, 0, stream>>>(c1_w, c1_b, n1_w, n1_b, c3_w, c3_b, an2_w, an2_b,
                                       fc1_w, fc1_b, n2_w, n2_b, sums);
  t0_kernel<<<784, 256, 0, stream>>>(x, xT, stats + 0);
  // G1: y = conv1(gn1(x)) -> yT CL, stats(y)
  sq128<256, 256, 0><<<dim3(2, 392), 256, 0, stream>>>(
      xT, wb_c1g, sums, sums + 256, stats + 0, stats + 32, nullptr, nullptr, yT);
  // e2g: tA = shift_w(fgelu(gn_as1(y))), tB = shift_h(...)
  e2g_kernel<<<2048, 256, 0, stream>>>(yT, tA, tB, an1_w, an1_b, stats + 32);
  // G2: z = fgelu(conv21(tA)) + fgelu(conv22(tB)) -> zT CL, stats(z)
  dual8<<<dim3(2, 392), 256, 0, stream>>>(tA, tB, wb_c21, wb_c22, c21_b, c22_b,
                                          stats + 64, zT);
  // G3: x2 = xT + conv3(gn_as2(z)) -> x2T CL, stats(x2)
  sq128<256, 256, 1><<<dim3(2, 392), 256, 0, stream>>>(
      zT, wb_c3g, sums + 512, sums + 768, stats + 64, stats + 96, xT, nullptr, x2T);
  // G4: hid = fgelu(fc1(gn2(x2))) -> hid CL [gpix][1024]
  sq128<256, 1024, 2><<<dim3(8, 392), 256, 0, stream>>>(
      x2T, wb_fc1g, sums + 1024, sums + 2048, stats + 96, nullptr, nullptr, nullptr, hid);
  // G5: out = x2 + fc2(hid) -> d_out f32 [n][c][hw]
  sq128<1024, 256, 3><<<dim3(2, 392), 256, 0, stream>>>(
      hid, wb_fc2, nullptr, fc2_b, nullptr, nullptr, x2T, out, nullptr);
}

// Round 12
// 282.908 us; speedup vs baseline: 2.0036x; 2.0036x over previous
//
#include <hip/hip_runtime.h>

typedef __attribute__((ext_vector_type(4))) float f32x4;
typedef __attribute__((ext_vector_type(8))) short bf16x8;
typedef __attribute__((ext_vector_type(4))) unsigned short u16x4;
typedef unsigned short u16;

#define HW 3136
#define NSEG 49
#define NELF 802816.0f
#define EPS 1e-5f

__device__ __forceinline__ short f2bf(float f) {
  union { float f; unsigned u; } v; v.f = f;
  unsigned r = (v.u + 0x7FFFu + ((v.u >> 16) & 1u)) >> 16;
  return (short)r;
}
__device__ __forceinline__ float b2f(u16 u) {
  union { unsigned u; float f; } v; v.u = ((unsigned)u) << 16;
  return v.f;
}
__device__ __forceinline__ float fgelu(float x) {
  float x2 = x * x;
  float u = x * (0.7978845608f + 0.0356774081f * x2);
  float e = __expf(-2.0f * u);
  return x * __builtin_amdgcn_rcpf(1.0f + e);
}
__device__ __forceinline__ void gload16(const void* g, void* l) {
  __builtin_amdgcn_global_load_lds(
      (const __attribute__((address_space(1))) void*)(uintptr_t)g,
      (__attribute__((address_space(3))) void*)(unsigned)(uintptr_t)l,
      16, 0, 0);
}

// ---- W0a: fold GN column scales into weights, convert to bf16 ----
__global__ void wfold_kernel(const float* __restrict__ c1, const float* __restrict__ c21,
                             const float* __restrict__ c22, const float* __restrict__ c3,
                             const float* __restrict__ fc1, const float* __restrict__ fc2,
                             const float* __restrict__ n1w, const float* __restrict__ an2w,
                             const float* __restrict__ n2w, u16* __restrict__ out) {
  int i = (blockIdx.x * 256 + threadIdx.x) * 4;
  const float* src; int off; const float* scale = nullptr;
  if (i < 65536)       { src = c1;  off = 0;       scale = n1w; }
  else if (i < 131072) { src = c21; off = 65536; }
  else if (i < 196608) { src = c22; off = 131072; }
  else if (i < 262144) { src = c3;  off = 196608;  scale = an2w; }
  else if (i < 524288) { src = fc1; off = 262144;  scale = n2w; }
  else                 { src = fc2; off = 524288; }
  int li = i - off;
  float4 v = *(const float4*)(src + li);
  if (scale) {
    float4 g = *(const float4*)(scale + (li & 255));
    v.x *= g.x; v.y *= g.y; v.z *= g.z; v.w *= g.w;
  }
  u16x4 o4; o4[0] = (u16)f2bf(v.x); o4[1] = (u16)f2bf(v.y); o4[2] = (u16)f2bf(v.z); o4[3] = (u16)f2bf(v.w);
  *(u16x4*)(out + i) = o4;
}

// ---- W0b: Sg/Sb row sums ----
__global__ void rowsum_kernel(const float* __restrict__ c1w, const float* __restrict__ c1b,
                              const float* __restrict__ n1w, const float* __restrict__ n1b,
                              const float* __restrict__ c3w, const float* __restrict__ c3b,
                              const float* __restrict__ an2w, const float* __restrict__ an2b,
                              const float* __restrict__ fc1w, const float* __restrict__ fc1b,
                              const float* __restrict__ n2w, const float* __restrict__ n2b,
                              float* __restrict__ sums) {
  int o = blockIdx.x * 256 + threadIdx.x;
  const float *W, *gw, *gb, *cb; float *Sg, *Sb; int row;
  if (o < 256)      { W = c1w;  gw = n1w;  gb = n1b;  cb = c1b;  Sg = sums;        Sb = sums + 256;  row = o; }
  else if (o < 512) { W = c3w;  gw = an2w; gb = an2b; cb = c3b;  Sg = sums + 512;  Sb = sums + 768;  row = o - 256; }
  else              { W = fc1w; gw = n2w;  gb = n2b;  cb = fc1b; Sg = sums + 1024; Sb = sums + 2048; row = o - 512; }
  float sg = 0.f, sb = 0.f;
  for (int c = 0; c < 256; c += 4) {
    float4 w = *(const float4*)(W + (size_t)row * 256 + c);
    float4 g = *(const float4*)(gw + c);
    float4 b = *(const float4*)(gb + c);
    sg += w.x * g.x + w.y * g.y + w.z * g.z + w.w * g.w;
    sb += w.x * b.x + w.y * b.y + w.z * b.z + w.w * b.w;
  }
  Sg[row] = sg; Sb[row] = sb + cb[row];
}

// ---- T0: stats(x) + transpose x -> xT bf16 [n][pix][c] ----
__global__ __launch_bounds__(256) void t0_kernel(const float* __restrict__ x,
                                                 u16* __restrict__ xT, float* __restrict__ st) {
  __shared__ __align__(16) u16 tile[64 * 256];
  const int t = threadIdx.x;
  const int n = blockIdx.x / NSEG;
  const int hw0 = (blockIdx.x % NSEG) * 64;
  const int pix = t & 63;
  float s = 0.f, q = 0.f;
#pragma unroll
  for (int r = 0; r < 16; ++r) {
    int cq = (t >> 6) + (r << 2);
    int c = cq * 4;
    u16x4 o4;
#pragma unroll
    for (int i = 0; i < 4; ++i) {
      float v = x[((size_t)n * 256 + c + i) * HW + hw0 + pix];
      s += v; q += v * v;
      o4[i] = (u16)f2bf(v);
    }
    int u = cq ^ ((pix & 15) << 2);
    *(u16x4*)((char*)tile + pix * 512 + u * 8) = o4;
  }
  __syncthreads();
  {
    const int p2 = t >> 2;
#pragma unroll
    for (int r = 0; r < 8; ++r) {
      int oct = (t & 3) + (r << 2);
      int up = (2 * oct) ^ ((p2 & 15) << 2);
      bf16x8 v = *(const bf16x8*)((char*)tile + p2 * 512 + up * 8);
      *(bf16x8*)&xT[((size_t)n * HW + hw0 + p2) * 256 + oct * 8] = v;
    }
  }
  __syncthreads();
  float* red = (float*)tile;
  red[t] = s; red[256 + t] = q;
  __syncthreads();
  for (int off = 128; off > 0; off >>= 1) {
    if (t < off) { red[t] += red[t + off]; red[256 + t] += red[256 + t + off]; }
    __syncthreads();
  }
  if (t == 0) { atomicAdd(&st[n * 2], red[0]); atomicAdd(&st[n * 2 + 1], red[256]); }
}

// ---- E2: t = fgelu(gn_as1(y)), channel-last elementwise ----
__global__ void e2_kernel(const u16* __restrict__ y, u16* __restrict__ tb,
                          const float* __restrict__ gw, const float* __restrict__ gb,
                          const float* __restrict__ stats) {
  const size_t NG = (size_t)16 * HW * 32;
  for (size_t g = (size_t)blockIdx.x * blockDim.x + threadIdx.x; g < NG;
       g += (size_t)gridDim.x * blockDim.x) {
    size_t base = g * 8;
    int n = (int)(base / 802816);
    int c0 = (int)(base & 255);
    float sm = stats[n * 2], sq = stats[n * 2 + 1];
    float mn = sm * (1.0f / NELF);
    float rstd = rsqrtf(sq * (1.0f / NELF) - mn * mn + EPS);
    bf16x8 v = *(const bf16x8*)(y + base);
    bf16x8 o;
#pragma unroll
    for (int j = 0; j < 8; ++j) {
      float sc = rstd * gw[c0 + j];
      float sh = gb[c0 + j] - mn * sc;
      o[j] = f2bf(fgelu(b2f((u16)v[j]) * sc + sh));
    }
    *(bf16x8*)(tb + base) = o;
  }
}

// ---- gemmW2: W resident in LDS, B via DMA dbuf, 512 thr, 256 out x 224 pix ----
// EPI: 0 = y (fold + store CL + stats) | 1 = x2 (fold + resid + store CL + stats)
template<int EPI>
__global__ __launch_bounds__(512, 2) void gemmW2(
    const u16* __restrict__ actT, const u16* __restrict__ wt,
    const float* __restrict__ Sg, const float* __restrict__ Sb,
    const float* __restrict__ stats_in, float* __restrict__ stats_out,
    const u16* __restrict__ residCL, u16* __restrict__ outT)
{
  __shared__ __align__(16) u16 lds[79872];   // W [0,65536); B dbuf [65536,72704),[72704,79872)
  const int t = threadIdx.x;
  const int lane = t & 63, wave = t >> 6;
  const int fr = lane & 15, fq = lane >> 4;
  const int wo = wave >> 1, wp = wave & 1;
  const int n = blockIdx.x / 14;
  const int hw0 = (blockIdx.x % 14) * 224;
  const size_t nHW = (size_t)n * HW;

  // W prologue
  {
    int u0 = t, u1 = t + 512;
    int r0 = u0 >> 2, sg0 = ((u0 & 3) - (r0 >> 1)) & 3;
    int r1 = u1 >> 2, sg1 = ((u1 & 3) - (r1 >> 1)) & 3;
    const u16* w0 = wt + (size_t)r0 * 256 + sg0 * 8;
    const u16* w1 = wt + (size_t)r1 * 256 + sg1 * 8;
#pragma unroll
    for (int k = 0; k < 8; ++k) {
      gload16(w0 + k * 32, &lds[k * 8192 + wave * 512]);
      gload16(w1 + k * 32, &lds[k * 8192 + 4096 + wave * 512]);
    }
  }

  int aU[4];
#pragma unroll
  for (int os = 0; os < 4; ++os) { int row = wo * 64 + os * 16 + fr; aU[os] = (4 * row + ((fq + (row >> 1)) & 3)) * 8; }
  int bO[7];
#pragma unroll
  for (int ps = 0; ps < 7; ++ps) {
    int pix = wp * 112 + ps * 16 + fr;
    bO[ps] = (pix * 4 + (fq ^ (pix & 3))) * 8;
  }

  // B staging: waves 0..6, slot v holds (p = v>>2, j = (v&3)^(p&3))
  const u16* srcB0; const u16* srcB1;
  {
    int v0 = wave * 128 + lane, v1 = v0 + 64;
    int p0 = v0 >> 2, j0 = (v0 & 3) ^ (p0 & 3);
    int p1 = v1 >> 2, j1 = (v1 & 3) ^ (p1 & 3);
    srcB0 = actT + (nHW + hw0 + p0) * 256 + j0 * 8;
    srcB1 = actT + (nHW + hw0 + p1) * 256 + j1 * 8;
  }
  auto stageB = [&](int par, int ks) {
    if (wave < 7) {
      gload16(srcB0 + ks * 32, &lds[65536 + par * 7168 + (wave * 128) * 8]);
      gload16(srcB1 + ks * 32, &lds[65536 + par * 7168 + (wave * 128 + 64) * 8]);
    }
  };

  f32x4 acc[4][7];
#pragma unroll
  for (int a = 0; a < 4; ++a)
#pragma unroll
    for (int b = 0; b < 7; ++b) acc[a][b] = (f32x4){0.f, 0.f, 0.f, 0.f};

  stageB(0, 0);
  __syncthreads();

#pragma unroll
  for (int k = 0; k < 8; ++k) {
    if (k < 7) stageB((k + 1) & 1, k + 1);
    bf16x8 afr[4], bfr[7];
#pragma unroll
    for (int os = 0; os < 4; ++os) afr[os] = *(const bf16x8*)&lds[k * 8192 + aU[os]];
#pragma unroll
    for (int ps = 0; ps < 7; ++ps) bfr[ps] = *(const bf16x8*)&lds[65536 + (k & 1) * 7168 + bO[ps]];
#pragma unroll
    for (int os = 0; os < 4; ++os)
#pragma unroll
      for (int ps = 0; ps < 7; ++ps)
        acc[os][ps] = __builtin_amdgcn_mfma_f32_16x16x32_bf16(afr[os], bfr[ps], acc[os][ps], 0, 0, 0);
    __syncthreads();
  }

  // epilogue: fold + (resid) + transpose store CL + stats
  char* tl = (char*)lds;
  float sm = stats_in[n * 2], sq = stats_in[n * 2 + 1];
  float mn = sm * (1.0f / NELF);
  float rstd = rsqrtf(sq * (1.0f / NELF) - mn * mn + EPS);
  float mr = mn * rstd;
  float lsum = 0.f, lsq = 0.f;
#pragma unroll
  for (int os = 0; os < 4; ++os) {
    const int ob = wo * 64 + os * 16 + fq * 4;
    float4 g4 = *(const float4*)&Sg[ob];
    float4 s4 = *(const float4*)&Sb[ob];
    float be[4] = {s4.x - mr * g4.x, s4.y - mr * g4.y, s4.z - mr * g4.z, s4.w - mr * g4.w};
#pragma unroll
    for (int ps = 0; ps < 7; ++ps) {
      const int pix = wp * 112 + ps * 16 + fr;
      u16x4 rv = {0, 0, 0, 0};
      if (EPI == 1) rv = *(const u16x4*)&residCL[(nHW + hw0 + pix) * 256 + ob];
      u16x4 pk;
#pragma unroll
      for (int j = 0; j < 4; ++j) {
        float v = fmaf(acc[os][ps][j], rstd, be[j]);
        if (EPI == 1) v += b2f(rv[j]);
        lsum += v; lsq += v * v;
        pk[j] = (u16)f2bf(v);
      }
      const int qd = wo * 16 + os * 4 + fq;
      const int uq = qd ^ ((pix & 15) << 2);
      *(u16x4*)(tl + pix * 512 + uq * 8) = pk;
    }
  }
  __syncthreads();
#pragma unroll
  for (int r = 0; r < 14; ++r) {
    int idx = t + r * 512;
    int pix = idx >> 5, oct = idx & 31;
    int up = (2 * oct) ^ ((pix & 15) << 2);
    bf16x8 v = *(const bf16x8*)(tl + pix * 512 + up * 8);
    *(bf16x8*)&outT[(nHW + hw0 + pix) * 256 + oct * 8] = v;
  }
  __syncthreads();
  float* red = (float*)lds;
  red[t] = lsum; red[512 + t] = lsq;
  __syncthreads();
  for (int off = 256; off > 0; off >>= 1) {
    if (t < off) { red[t] += red[t + off]; red[512 + t] += red[512 + t + off]; }
    __syncthreads();
  }
  if (t == 0) { atomicAdd(&stats_out[n * 2], red[0]); atomicAdd(&stats_out[n * 2 + 1], red[512]); }
}

// ---- gemm_dual4: z = fgelu(conv21(shift_w t)) + fgelu(conv22(shift_h t)), 256 out x 112 pix ----
__global__ __launch_bounds__(512, 2) void gemm_dual4(
    const u16* __restrict__ tT, const u16* __restrict__ w21, const u16* __restrict__ w22,
    const float* __restrict__ b21, const float* __restrict__ b22,
    float* __restrict__ stats_out, u16* __restrict__ zT)
{
  // W21 dbuf [0,16384); W22 dbuf [16384,32768); tA dbuf [32768,+2*3712); tB dbuf [40192,+2*3712)
  __shared__ __align__(16) u16 lds[47616];
  const int t = threadIdx.x;
  const int lane = t & 63, wave = t >> 6;
  const int fr = lane & 15, fq = lane >> 4;
  const int n = blockIdx.x / 28;
  const int hw0 = (blockIdx.x % 28) * 112;
  const size_t nHW = (size_t)n * HW;

  // gather role: thread handles unit u=(jl,p); dummy for t>=448 (uniform load count)
  const int u = (t < 448) ? t : 447;
  const int jl = u / 112, p = u - jl * 112;
  const int pix = hw0 + p;
  const int wc = pix % 56, hc = pix / 56;

  bf16x8 gA0, gA1, gB0, gB1;
  auto gatherIssue = [&](int ks) {
    int c0 = ks * 32 + jl * 8;
    int g0 = c0 / 37;
    int s0 = 3 - g0;
    int pa0 = pix + s0;           pa0 = pa0 < 0 ? 0 : (pa0 > HW - 1 ? HW - 1 : pa0);
    int pa1 = pix + s0 - 1;       pa1 = pa1 < 0 ? 0 : (pa1 > HW - 1 ? HW - 1 : pa1);
    int pb0 = pix + 56 * s0;      pb0 = pb0 < 0 ? 0 : (pb0 > HW - 1 ? HW - 1 : pb0);
    int pb1 = pix + 56 * (s0 - 1); pb1 = pb1 < 0 ? 0 : (pb1 > HW - 1 ? HW - 1 : pb1);
    gA0 = *(const bf16x8*)(tT + (nHW + pa0) * 256 + c0);
    gA1 = *(const bf16x8*)(tT + (nHW + pa1) * 256 + c0);
    gB0 = *(const bf16x8*)(tT + (nHW + pb0) * 256 + c0);
    gB1 = *(const bf16x8*)(tT + (nHW + pb1) * 256 + c0);
  };
  auto gatherWrite = [&](int par, int ks) {
    int c0 = ks * 32 + jl * 8;
    int g0 = c0 / 37;
    int s0 = 3 - g0;
    int js = (g0 + 1) * 37 - c0; if (js > 8) js = 8;
    bool a0 = (unsigned)(wc + s0) < 56u, a1 = (unsigned)(wc + s0 - 1) < 56u;
    bool b0 = (unsigned)(hc + s0) < 56u, b1 = (unsigned)(hc + s0 - 1) < 56u;
    bf16x8 va, vb;
#pragma unroll
    for (int j = 0; j < 8; ++j) {
      bool lo = j < js;
      va[j] = lo ? (a0 ? gA0[j] : (short)0) : (a1 ? gA1[j] : (short)0);
      vb[j] = lo ? (b0 ? gB0[j] : (short)0) : (b1 ? gB1[j] : (short)0);
    }
    if (t < 448) {
      *(bf16x8*)&lds[32768 + par * 3712 + (jl * 116 + p) * 8] = va;
      *(bf16x8*)&lds[40192 + par * 3712 + (jl * 116 + p) * 8] = vb;
    }
  };
  auto stageW = [&](int par, int ks) {
    int u0 = t; int r0 = u0 >> 2, sg0 = ((u0 & 3) - (r0 >> 1)) & 3;
    int u1 = t + 512; int r1 = u1 >> 2, sg1 = ((u1 & 3) - (r1 >> 1)) & 3;
    gload16(w21 + (size_t)r0 * 256 + ks * 32 + sg0 * 8, &lds[par * 8192 + wave * 512]);
    gload16(w21 + (size_t)r1 * 256 + ks * 32 + sg1 * 8, &lds[par * 8192 + 4096 + wave * 512]);
    gload16(w22 + (size_t)r0 * 256 + ks * 32 + sg0 * 8, &lds[16384 + par * 8192 + wave * 512]);
    gload16(w22 + (size_t)r1 * 256 + ks * 32 + sg1 * 8, &lds[16384 + par * 8192 + 4096 + wave * 512]);
  };

  int aU[2], bP[7];
#pragma unroll
  for (int os = 0; os < 2; ++os) { int row = wave * 32 + os * 16 + fr; aU[os] = (4 * row + ((fq + (row >> 1)) & 3)) * 8; }
#pragma unroll
  for (int ps = 0; ps < 7; ++ps) bP[ps] = (fq * 116 + ps * 16 + fr) * 8;

  f32x4 accA[2][7], accB[2][7];
#pragma unroll
  for (int a = 0; a < 2; ++a)
#pragma unroll
    for (int b = 0; b < 7; ++b) { accA[a][b] = (f32x4){0, 0, 0, 0}; accB[a][b] = (f32x4){0, 0, 0, 0}; }

  // prologue
  gatherIssue(0);
  stageW(0, 0);
  gatherWrite(0, 0);
  gatherIssue(1);
  __syncthreads();

#pragma unroll
  for (int k = 0; k < 8; ++k) {
    if (k < 7) stageW((k + 1) & 1, k + 1);
    bf16x8 afA[2], afB[2], bfA[7], bfB[7];
#pragma unroll
    for (int os = 0; os < 2; ++os) {
      afA[os] = *(const bf16x8*)&lds[(k & 1) * 8192 + aU[os]];
      afB[os] = *(const bf16x8*)&lds[16384 + (k & 1) * 8192 + aU[os]];
    }
#pragma unroll
    for (int ps = 0; ps < 7; ++ps) {
      bfA[ps] = *(const bf16x8*)&lds[32768 + (k & 1) * 3712 + bP[ps]];
      bfB[ps] = *(const bf16x8*)&lds[40192 + (k & 1) * 3712 + bP[ps]];
    }
#pragma unroll
    for (int os = 0; os < 2; ++os)
#pragma unroll
      for (int ps = 0; ps < 7; ++ps) {
        accA[os][ps] = __builtin_amdgcn_mfma_f32_16x16x32_bf16(afA[os], bfA[ps], accA[os][ps], 0, 0, 0);
        accB[os][ps] = __builtin_amdgcn_mfma_f32_16x16x32_bf16(afB[os], bfB[ps], accB[os][ps], 0, 0, 0);
      }
    if (k < 7) {
      gatherWrite((k + 1) & 1, k + 1);
      if (k < 6) gatherIssue(k + 2);
    }
    __syncthreads();
  }

  // epilogue: z + transpose store + stats
  char* tl = (char*)lds;
  float lsum = 0.f, lsq = 0.f;
#pragma unroll
  for (int os = 0; os < 2; ++os) {
    const int ob = wave * 32 + os * 16 + fq * 4;
    float4 a4 = *(const float4*)&b21[ob];
    float4 c4 = *(const float4*)&b22[ob];
    float ba[4] = {a4.x, a4.y, a4.z, a4.w};
    float bb[4] = {c4.x, c4.y, c4.z, c4.w};
#pragma unroll
    for (int ps = 0; ps < 7; ++ps) {
      const int pixL = ps * 16 + fr;
      u16x4 pk;
#pragma unroll
      for (int j = 0; j < 4; ++j) {
        float z = fgelu(accA[os][ps][j] + ba[j]) + fgelu(accB[os][ps][j] + bb[j]);
        lsum += z; lsq += z * z;
        pk[j] = (u16)f2bf(z);
      }
      const int qd = wave * 8 + os * 4 + fq;
      const int uq = qd ^ ((pixL & 15) << 2);
      *(u16x4*)(tl + pixL * 512 + uq * 8) = pk;
    }
  }
  __syncthreads();
#pragma unroll
  for (int r = 0; r < 7; ++r) {
    int idx = t + r * 512;
    int pixL = idx >> 5, oct = idx & 31;
    int up = (2 * oct) ^ ((pixL & 15) << 2);
    bf16x8 v = *(const bf16x8*)(tl + pixL * 512 + up * 8);
    *(bf16x8*)&zT[(nHW + hw0 + pixL) * 256 + oct * 8] = v;
  }
  __syncthreads();
  float* red = (float*)lds;
  red[t] = lsum; red[512 + t] = lsq;
  __syncthreads();
  for (int off = 256; off > 0; off >>= 1) {
    if (t < off) { red[t] += red[t + off]; red[512 + t] += red[512 + t + off]; }
    __syncthreads();
  }
  if (t == 0) { atomicAdd(&stats_out[n * 2], red[0]); atomicAdd(&stats_out[n * 2 + 1], red[512]); }
}

// ---- gemm_mlp: out = x2 + fc2(fgelu(fc1(gn2(x2)))) fused; hid never leaves LDS ----
__global__ __launch_bounds__(512, 2) void gemm_mlp(
    const u16* __restrict__ x2T, const u16* __restrict__ wfc1, const u16* __restrict__ wfc2,
    const float* __restrict__ Sg, const float* __restrict__ Sb, const float* __restrict__ bias2,
    const float* __restrict__ stats_in, float* __restrict__ out_f32)
{
  // W dbuf [0,16384); B1 (x2 tile, stride 113) [16384,45312); H (stride 116) [45312,75008)
  __shared__ __align__(16) u16 lds[75008];
  const int t = threadIdx.x;
  const int lane = t & 63, wave = t >> 6;
  const int fr = lane & 15, fq = lane >> 4;
  const int n = blockIdx.x / 28;
  const int hw0 = (blockIdx.x % 28) * 112;
  const size_t nHW = (size_t)n * HW;

  auto stageWm = [&](int par, int s) {
    int chunk = s >> 4, kk = s & 7;
    int u0 = t; int r0 = u0 >> 2, sg0 = ((u0 & 3) - (r0 >> 1)) & 3;
    int u1 = t + 512; int r1 = u1 >> 2, sg1 = ((u1 & 3) - (r1 >> 1)) & 3;
    if (((s >> 3) & 1) == 0) {
      gload16(wfc1 + (size_t)(chunk * 256 + r0) * 256 + kk * 32 + sg0 * 8, &lds[par * 8192 + wave * 512]);
      gload16(wfc1 + (size_t)(chunk * 256 + r1) * 256 + kk * 32 + sg1 * 8, &lds[par * 8192 + 4096 + wave * 512]);
    } else {
      gload16(wfc2 + (size_t)r0 * 1024 + chunk * 256 + kk * 32 + sg0 * 8, &lds[par * 8192 + wave * 512]);
      gload16(wfc2 + (size_t)r1 * 1024 + chunk * 256 + kk * 32 + sg1 * 8, &lds[par * 8192 + 4096 + wave * 512]);
    }
  };

  // B1 prologue (reg-staged, padded stride 113 -> conflict-free reads)
#pragma unroll
  for (int i = 0; i < 7; ++i) {
    int u = wave * 448 + i * 64 + lane;
    int j = u / 112, p = u - j * 112;
    bf16x8 v = *(const bf16x8*)(x2T + (nHW + hw0 + p) * 256 + j * 8);
    *(bf16x8*)&lds[16384 + (j * 113 + p) * 8] = v;
  }
  stageWm(0, 0);

  float sm = stats_in[n * 2], sq = stats_in[n * 2 + 1];
  float mn = sm * (1.0f / NELF);
  float rstd = rsqrtf(sq * (1.0f / NELF) - mn * mn + EPS);
  float mr = mn * rstd;

  int aU[2];
#pragma unroll
  for (int os = 0; os < 2; ++os) { int row = wave * 32 + os * 16 + fr; aU[os] = (4 * row + ((fq + (row >> 1)) & 3)) * 8; }

  f32x4 hacc[2][7], oacc[2][7];
#pragma unroll
  for (int a = 0; a < 2; ++a)
#pragma unroll
    for (int b = 0; b < 7; ++b) { hacc[a][b] = (f32x4){0, 0, 0, 0}; oacc[a][b] = (f32x4){0, 0, 0, 0}; }

  __syncthreads();

  for (int s = 0; s < 64; ++s) {
    if (s < 63) stageWm((s + 1) & 1, s + 1);
    const int kk = s & 7;
    const bool bph = (s >> 3) & 1;
    bf16x8 afr[2], bfr[7];
#pragma unroll
    for (int os = 0; os < 2; ++os) afr[os] = *(const bf16x8*)&lds[(s & 1) * 8192 + aU[os]];
    if (!bph) {
#pragma unroll
      for (int ps = 0; ps < 7; ++ps)
        bfr[ps] = *(const bf16x8*)&lds[16384 + ((kk * 4 + fq) * 113 + ps * 16 + fr) * 8];
#pragma unroll
      for (int os = 0; os < 2; ++os)
#pragma unroll
        for (int ps = 0; ps < 7; ++ps)
          hacc[os][ps] = __builtin_amdgcn_mfma_f32_16x16x32_bf16(afr[os], bfr[ps], hacc[os][ps], 0, 0, 0);
    } else {
#pragma unroll
      for (int ps = 0; ps < 7; ++ps)
        bfr[ps] = *(const bf16x8*)&lds[45312 + ((kk * 4 + fq) * 116 + ps * 16 + fr) * 8];
#pragma unroll
      for (int os = 0; os < 2; ++os)
#pragma unroll
        for (int ps = 0; ps < 7; ++ps)
          oacc[os][ps] = __builtin_amdgcn_mfma_f32_16x16x32_bf16(afr[os], bfr[ps], oacc[os][ps], 0, 0, 0);
    }
    if ((s & 15) == 7) {
      // A-phase of chunk done: hid = fgelu(rstd*hacc + be) -> H plane, reset hacc
      const int hcb = (s >> 4) * 256;
#pragma unroll
      for (int os = 0; os < 2; ++os) {
        const int hcl = wave * 32 + os * 16 + fq * 4;
        const int hc = hcb + hcl;
        float4 g4 = *(const float4*)&Sg[hc];
        float4 s4 = *(const float4*)&Sb[hc];
        float be[4] = {s4.x - mr * g4.x, s4.y - mr * g4.y, s4.z - mr * g4.z, s4.w - mr * g4.w};
        const int jH = hcl >> 3;
#pragma unroll
        for (int ps = 0; ps < 7; ++ps) {
          const int pixL = ps * 16 + fr;
          u16x4 pk;
#pragma unroll
          for (int j = 0; j < 4; ++j)
            pk[j] = (u16)f2bf(fgelu(fmaf(hacc[os][ps][j], rstd, be[j])));
          *(u16x4*)&lds[45312 + (jH * 116 + pixL) * 8 + (fq & 1) * 4] = pk;
          hacc[os][ps] = (f32x4){0, 0, 0, 0};
        }
      }
    }
    __syncthreads();
  }

  // epilogue: out = oacc + bias + x2 (resid from B1 plane)
#pragma unroll
  for (int os = 0; os < 2; ++os) {
    const int ob = wave * 32 + os * 16 + fq * 4;
    float4 b4 = *(const float4*)&bias2[ob];
    float bb[4] = {b4.x, b4.y, b4.z, b4.w};
#pragma unroll
    for (int ps = 0; ps < 7; ++ps) {
      const int pixL = ps * 16 + fr;
      u16x4 rv = *(const u16x4*)&lds[16384 + ((ob >> 3) * 113 + pixL) * 8 + (ob & 4)];
#pragma unroll
      for (int j = 0; j < 4; ++j) {
        float v = oacc[os][ps][j] + bb[j] + b2f(rv[j]);
        out_f32[((size_t)n * 256 + ob + j) * HW + hw0 + pixL] = v;
      }
    }
  }
}

extern "C" void kernel_launch(void* const* d_in, const int* in_sizes, int n_in,
                              void* d_out, int out_size, void* d_ws, size_t ws_size,
                              hipStream_t stream) {
  const float* x     = (const float*)d_in[0];
  const float* n1_w  = (const float*)d_in[1];
  const float* n1_b  = (const float*)d_in[2];
  const float* c1_w  = (const float*)d_in[3];
  const float* c1_b  = (const float*)d_in[4];
  const float* an1_w = (const float*)d_in[5];
  const float* an1_b = (const float*)d_in[6];
  const float* c21_w = (const float*)d_in[7];
  const float* c21_b = (const float*)d_in[8];
  const float* c22_w = (const float*)d_in[9];
  const float* c22_b = (const float*)d_in[10];
  const float* an2_w = (const float*)d_in[11];
  const float* an2_b = (const float*)d_in[12];
  const float* c3_w  = (const float*)d_in[13];
  const float* c3_b  = (const float*)d_in[14];
  const float* n2_w  = (const float*)d_in[15];
  const float* n2_b  = (const float*)d_in[16];
  const float* fc1_w = (const float*)d_in[17];
  const float* fc1_b = (const float*)d_in[18];
  const float* fc2_w = (const float*)d_in[19];
  const float* fc2_b = (const float*)d_in[20];

  char* ws = (char*)d_ws;
  float* stats = (float*)ws;
  float* sums  = (float*)(ws + 1024);
  u16* wbuf = (u16*)(ws + 16384);
  u16* wb_c1g  = wbuf;
  u16* wb_c21  = wbuf + 65536;
  u16* wb_c22  = wbuf + 131072;
  u16* wb_c3g  = wbuf + 196608;
  u16* wb_fc1g = wbuf + 262144;
  u16* wb_fc2  = wbuf + 524288;
  const size_t AB = 25690112;
  char* A0 = ws + 1638400;
  u16* xT  = (u16*)(A0);
  u16* yT  = (u16*)(A0 + AB);
  u16* tT  = (u16*)(A0 + 2 * AB);
  u16* zT  = (u16*)(A0 + 3 * AB);
  u16* x2T = (u16*)(A0 + 4 * AB);
  float* out = (float*)d_out;

  hipMemsetAsync(stats, 0, 512, stream);
  wfold_kernel<<<768, 256, 0, stream>>>(c1_w, c21_w, c22_w, c3_w, fc1_w, fc2_w,
                                        n1_w, an2_w, n2_w, wbuf);
  rowsum_kernel<<<6, 256, 0, stream>>>(c1_w, c1_b, n1_w, n1_b, c3_w, c3_b, an2_w, an2_b,
                                       fc1_w, fc1_b, n2_w, n2_b, sums);
  t0_kernel<<<784, 256, 0, stream>>>(x, xT, stats + 0);
  // G1: y = conv1(gn1(x)) -> yT CL, stats(y)
  gemmW2<0><<<224, 512, 0, stream>>>(xT, wb_c1g, sums, sums + 256,
                                     stats + 0, stats + 32, nullptr, yT);
  // E2: t = fgelu(gn_as1(y)) -> tT CL
  e2_kernel<<<2048, 256, 0, stream>>>(yT, tT, an1_w, an1_b, stats + 32);
  // G2: z = fgelu(conv21(shift_w t)) + fgelu(conv22(shift_h t)) -> zT CL, stats(z)
  gemm_dual4<<<448, 512, 0, stream>>>(tT, wb_c21, wb_c22, c21_b, c22_b, stats + 64, zT);
  // G3: x2 = xT + conv3(gn_as2(z)) -> x2T CL, stats(x2)
  gemmW2<1><<<224, 512, 0, stream>>>(zT, wb_c3g, sums + 512, sums + 768,
                                     stats + 64, stats + 96, xT, x2T);
  // G4+G5 fused: out = x2 + fc2(fgelu(fc1(gn2(x2)))) -> d_out f32
  gemm_mlp<<<448, 512, 0, stream>>>(x2T, wb_fc1g, wb_fc2, sums + 1024, sums + 2048,
                                    fc2_b, stats + 96, out);
}

// Round 13
// 264.824 us; speedup vs baseline: 2.1404x; 1.0683x over previous
//
#include <hip/hip_runtime.h>

typedef __attribute__((ext_vector_type(4))) float f32x4;
typedef __attribute__((ext_vector_type(8))) short bf16x8;
typedef __attribute__((ext_vector_type(4))) unsigned short u16x4;
typedef unsigned short u16;

#define HW 3136
#define NSEG 49
#define NELF 802816.0f
#define EPS 1e-5f

__device__ __forceinline__ short f2bf(float f) {
  union { float f; unsigned u; } v; v.f = f;
  unsigned r = (v.u + 0x7FFFu + ((v.u >> 16) & 1u)) >> 16;
  return (short)r;
}
__device__ __forceinline__ float b2f(u16 u) {
  union { unsigned u; float f; } v; v.u = ((unsigned)u) << 16;
  return v.f;
}
__device__ __forceinline__ float fgelu(float x) {
  float x2 = x * x;
  float u = x * (0.7978845608f + 0.0356774081f * x2);
  float e = __expf(-2.0f * u);
  return x * __builtin_amdgcn_rcpf(1.0f + e);
}
__device__ __forceinline__ void gload16(const void* g, void* l) {
  __builtin_amdgcn_global_load_lds(
      (const __attribute__((address_space(1))) void*)(uintptr_t)g,
      (__attribute__((address_space(3))) void*)(unsigned)(uintptr_t)l,
      16, 0, 0);
}

// ---- W0a: fold GN column scales into weights, convert to bf16 ----
__global__ void wfold_kernel(const float* __restrict__ c1, const float* __restrict__ c21,
                             const float* __restrict__ c22, const float* __restrict__ c3,
                             const float* __restrict__ fc1, const float* __restrict__ fc2,
                             const float* __restrict__ n1w, const float* __restrict__ an2w,
                             const float* __restrict__ n2w, u16* __restrict__ out) {
  int i = (blockIdx.x * 256 + threadIdx.x) * 4;
  const float* src; int off; const float* scale = nullptr;
  if (i < 65536)       { src = c1;  off = 0;       scale = n1w; }
  else if (i < 131072) { src = c21; off = 65536; }
  else if (i < 196608) { src = c22; off = 131072; }
  else if (i < 262144) { src = c3;  off = 196608;  scale = an2w; }
  else if (i < 524288) { src = fc1; off = 262144;  scale = n2w; }
  else                 { src = fc2; off = 524288; }
  int li = i - off;
  float4 v = *(const float4*)(src + li);
  if (scale) {
    float4 g = *(const float4*)(scale + (li & 255));
    v.x *= g.x; v.y *= g.y; v.z *= g.z; v.w *= g.w;
  }
  u16x4 o4; o4[0] = (u16)f2bf(v.x); o4[1] = (u16)f2bf(v.y); o4[2] = (u16)f2bf(v.z); o4[3] = (u16)f2bf(v.w);
  *(u16x4*)(out + i) = o4;
}

// ---- W0b: Sg/Sb row sums ----
__global__ void rowsum_kernel(const float* __restrict__ c1w, const float* __restrict__ c1b,
                              const float* __restrict__ n1w, const float* __restrict__ n1b,
                              const float* __restrict__ c3w, const float* __restrict__ c3b,
                              const float* __restrict__ an2w, const float* __restrict__ an2b,
                              const float* __restrict__ fc1w, const float* __restrict__ fc1b,
                              const float* __restrict__ n2w, const float* __restrict__ n2b,
                              float* __restrict__ sums) {
  int o = blockIdx.x * 256 + threadIdx.x;
  const float *W, *gw, *gb, *cb; float *Sg, *Sb; int row;
  if (o < 256)      { W = c1w;  gw = n1w;  gb = n1b;  cb = c1b;  Sg = sums;        Sb = sums + 256;  row = o; }
  else if (o < 512) { W = c3w;  gw = an2w; gb = an2b; cb = c3b;  Sg = sums + 512;  Sb = sums + 768;  row = o - 256; }
  else              { W = fc1w; gw = n2w;  gb = n2b;  cb = fc1b; Sg = sums + 1024; Sb = sums + 2048; row = o - 512; }
  float sg = 0.f, sb = 0.f;
  for (int c = 0; c < 256; c += 4) {
    float4 w = *(const float4*)(W + (size_t)row * 256 + c);
    float4 g = *(const float4*)(gw + c);
    float4 b = *(const float4*)(gb + c);
    sg += w.x * g.x + w.y * g.y + w.z * g.z + w.w * g.w;
    sb += w.x * b.x + w.y * b.y + w.z * b.z + w.w * b.w;
  }
  Sg[row] = sg; Sb[row] = sb + cb[row];
}

// ---- T0: stats(x) + transpose x -> xT bf16 [n][pix][c] ----
__global__ __launch_bounds__(256) void t0_kernel(const float* __restrict__ x,
                                                 u16* __restrict__ xT, float* __restrict__ st) {
  __shared__ __align__(16) u16 tile[64 * 256];
  const int t = threadIdx.x;
  const int n = blockIdx.x / NSEG;
  const int hw0 = (blockIdx.x % NSEG) * 64;
  const int pix = t & 63;
  float s = 0.f, q = 0.f;
#pragma unroll
  for (int r = 0; r < 16; ++r) {
    int cq = (t >> 6) + (r << 2);
    int c = cq * 4;
    u16x4 o4;
#pragma unroll
    for (int i = 0; i < 4; ++i) {
      float v = x[((size_t)n * 256 + c + i) * HW + hw0 + pix];
      s += v; q += v * v;
      o4[i] = (u16)f2bf(v);
    }
    int u = cq ^ ((pix & 15) << 2);
    *(u16x4*)((char*)tile + pix * 512 + u * 8) = o4;
  }
  __syncthreads();
  {
    const int p2 = t >> 2;
#pragma unroll
    for (int r = 0; r < 8; ++r) {
      int oct = (t & 3) + (r << 2);
      int up = (2 * oct) ^ ((p2 & 15) << 2);
      bf16x8 v = *(const bf16x8*)((char*)tile + p2 * 512 + up * 8);
      *(bf16x8*)&xT[((size_t)n * HW + hw0 + p2) * 256 + oct * 8] = v;
    }
  }
  __syncthreads();
  float* red = (float*)tile;
  red[t] = s; red[256 + t] = q;
  __syncthreads();
  for (int off = 128; off > 0; off >>= 1) {
    if (t < off) { red[t] += red[t + off]; red[256 + t] += red[256 + t + off]; }
    __syncthreads();
  }
  if (t == 0) { atomicAdd(&st[n * 2], red[0]); atomicAdd(&st[n * 2 + 1], red[256]); }
}

// ---- E2: t = fgelu(gn_as1(y)), channel-last elementwise ----
__global__ void e2_kernel(const u16* __restrict__ y, u16* __restrict__ tb,
                          const float* __restrict__ gw, const float* __restrict__ gb,
                          const float* __restrict__ stats) {
  const size_t NG = (size_t)16 * HW * 32;
  for (size_t g = (size_t)blockIdx.x * blockDim.x + threadIdx.x; g < NG;
       g += (size_t)gridDim.x * blockDim.x) {
    size_t base = g * 8;
    int n = (int)(base / 802816);
    int c0 = (int)(base & 255);
    float sm = stats[n * 2], sq = stats[n * 2 + 1];
    float mn = sm * (1.0f / NELF);
    float rstd = rsqrtf(sq * (1.0f / NELF) - mn * mn + EPS);
    bf16x8 v = *(const bf16x8*)(y + base);
    bf16x8 o;
#pragma unroll
    for (int j = 0; j < 8; ++j) {
      float sc = rstd * gw[c0 + j];
      float sh = gb[c0 + j] - mn * sc;
      o[j] = f2bf(fgelu(b2f((u16)v[j]) * sc + sh));
    }
    *(bf16x8*)(tb + base) = o;
  }
}

// ---- gemmW2: W resident in LDS, B via DMA dbuf, 512 thr, 256 out x 224 pix ----
// EPI: 0 = y (fold + store CL + stats) | 1 = x2 (fold + resid + store CL + stats)
template<int EPI>
__global__ __launch_bounds__(512, 2) void gemmW2(
    const u16* __restrict__ actT, const u16* __restrict__ wt,
    const float* __restrict__ Sg, const float* __restrict__ Sb,
    const float* __restrict__ stats_in, float* __restrict__ stats_out,
    const u16* __restrict__ residCL, u16* __restrict__ outT)
{
  __shared__ __align__(16) u16 lds[79872];   // W [0,65536); B dbuf [65536,72704),[72704,79872)
  const int t = threadIdx.x;
  const int lane = t & 63, wave = t >> 6;
  const int fr = lane & 15, fq = lane >> 4;
  const int wo = wave >> 1, wp = wave & 1;
  const int n = blockIdx.x / 14;
  const int hw0 = (blockIdx.x % 14) * 224;
  const size_t nHW = (size_t)n * HW;

  // W prologue
  {
    int u0 = t, u1 = t + 512;
    int r0 = u0 >> 2, sg0 = ((u0 & 3) - (r0 >> 1)) & 3;
    int r1 = u1 >> 2, sg1 = ((u1 & 3) - (r1 >> 1)) & 3;
    const u16* w0 = wt + (size_t)r0 * 256 + sg0 * 8;
    const u16* w1 = wt + (size_t)r1 * 256 + sg1 * 8;
#pragma unroll
    for (int k = 0; k < 8; ++k) {
      gload16(w0 + k * 32, &lds[k * 8192 + wave * 512]);
      gload16(w1 + k * 32, &lds[k * 8192 + 4096 + wave * 512]);
    }
  }

  int aU[4];
#pragma unroll
  for (int os = 0; os < 4; ++os) { int row = wo * 64 + os * 16 + fr; aU[os] = (4 * row + ((fq + (row >> 1)) & 3)) * 8; }
  int bO[7];
#pragma unroll
  for (int ps = 0; ps < 7; ++ps) {
    int pix = wp * 112 + ps * 16 + fr;
    bO[ps] = (pix * 4 + (fq ^ (pix & 3))) * 8;
  }

  // B staging: waves 0..6, slot v holds (p = v>>2, j = (v&3)^(p&3))
  const u16* srcB0; const u16* srcB1;
  {
    int v0 = wave * 128 + lane, v1 = v0 + 64;
    int p0 = v0 >> 2, j0 = (v0 & 3) ^ (p0 & 3);
    int p1 = v1 >> 2, j1 = (v1 & 3) ^ (p1 & 3);
    srcB0 = actT + (nHW + hw0 + p0) * 256 + j0 * 8;
    srcB1 = actT + (nHW + hw0 + p1) * 256 + j1 * 8;
  }
  auto stageB = [&](int par, int ks) {
    if (wave < 7) {
      gload16(srcB0 + ks * 32, &lds[65536 + par * 7168 + (wave * 128) * 8]);
      gload16(srcB1 + ks * 32, &lds[65536 + par * 7168 + (wave * 128 + 64) * 8]);
    }
  };

  f32x4 acc[4][7];
#pragma unroll
  for (int a = 0; a < 4; ++a)
#pragma unroll
    for (int b = 0; b < 7; ++b) acc[a][b] = (f32x4){0.f, 0.f, 0.f, 0.f};

  stageB(0, 0);
  __syncthreads();

#pragma unroll
  for (int k = 0; k < 8; ++k) {
    if (k < 7) stageB((k + 1) & 1, k + 1);
    bf16x8 afr[4], bfr[7];
#pragma unroll
    for (int os = 0; os < 4; ++os) afr[os] = *(const bf16x8*)&lds[k * 8192 + aU[os]];
#pragma unroll
    for (int ps = 0; ps < 7; ++ps) bfr[ps] = *(const bf16x8*)&lds[65536 + (k & 1) * 7168 + bO[ps]];
#pragma unroll
    for (int os = 0; os < 4; ++os)
#pragma unroll
      for (int ps = 0; ps < 7; ++ps)
        acc[os][ps] = __builtin_amdgcn_mfma_f32_16x16x32_bf16(afr[os], bfr[ps], acc[os][ps], 0, 0, 0);
    __syncthreads();
  }

  // epilogue: fold + (resid) + transpose store CL + stats
  char* tl = (char*)lds;
  float sm = stats_in[n * 2], sq = stats_in[n * 2 + 1];
  float mn = sm * (1.0f / NELF);
  float rstd = rsqrtf(sq * (1.0f / NELF) - mn * mn + EPS);
  float mr = mn * rstd;
  float lsum = 0.f, lsq = 0.f;
#pragma unroll
  for (int os = 0; os < 4; ++os) {
    const int ob = wo * 64 + os * 16 + fq * 4;
    float4 g4 = *(const float4*)&Sg[ob];
    float4 s4 = *(const float4*)&Sb[ob];
    float be[4] = {s4.x - mr * g4.x, s4.y - mr * g4.y, s4.z - mr * g4.z, s4.w - mr * g4.w};
#pragma unroll
    for (int ps = 0; ps < 7; ++ps) {
      const int pix = wp * 112 + ps * 16 + fr;
      u16x4 rv = {0, 0, 0, 0};
      if (EPI == 1) rv = *(const u16x4*)&residCL[(nHW + hw0 + pix) * 256 + ob];
      u16x4 pk;
#pragma unroll
      for (int j = 0; j < 4; ++j) {
        float v = fmaf(acc[os][ps][j], rstd, be[j]);
        if (EPI == 1) v += b2f(rv[j]);
        lsum += v; lsq += v * v;
        pk[j] = (u16)f2bf(v);
      }
      const int qd = wo * 16 + os * 4 + fq;
      const int uq = qd ^ ((pix & 15) << 2);
      *(u16x4*)(tl + pix * 512 + uq * 8) = pk;
    }
  }
  __syncthreads();
#pragma unroll
  for (int r = 0; r < 14; ++r) {
    int idx = t + r * 512;
    int pix = idx >> 5, oct = idx & 31;
    int up = (2 * oct) ^ ((pix & 15) << 2);
    bf16x8 v = *(const bf16x8*)(tl + pix * 512 + up * 8);
    *(bf16x8*)&outT[(nHW + hw0 + pix) * 256 + oct * 8] = v;
  }
  __syncthreads();
  float* red = (float*)lds;
  red[t] = lsum; red[512 + t] = lsq;
  __syncthreads();
  for (int off = 256; off > 0; off >>= 1) {
    if (t < off) { red[t] += red[t + off]; red[512 + t] += red[512 + t + off]; }
    __syncthreads();
  }
  if (t == 0) { atomicAdd(&stats_out[n * 2], red[0]); atomicAdd(&stats_out[n * 2 + 1], red[512]); }
}

// ---- gemm_dual4: z = fgelu(conv21(shift_w t)) + fgelu(conv22(shift_h t)), 256 out x 112 pix ----
__global__ __launch_bounds__(512, 2) void gemm_dual4(
    const u16* __restrict__ tT, const u16* __restrict__ w21, const u16* __restrict__ w22,
    const float* __restrict__ b21, const float* __restrict__ b22,
    float* __restrict__ stats_out, u16* __restrict__ zT)
{
  // W21 dbuf [0,16384); W22 dbuf [16384,32768); tA dbuf [32768,+2*3712); tB dbuf [40192,+2*3712)
  __shared__ __align__(16) u16 lds[47616];
  const int t = threadIdx.x;
  const int lane = t & 63, wave = t >> 6;
  const int fr = lane & 15, fq = lane >> 4;
  const int n = blockIdx.x / 28;
  const int hw0 = (blockIdx.x % 28) * 112;
  const size_t nHW = (size_t)n * HW;

  // gather role: thread handles unit u=(jl,p); dummy for t>=448 (uniform load count)
  const int u = (t < 448) ? t : 447;
  const int jl = u / 112, p = u - jl * 112;
  const int pix = hw0 + p;
  const int wc = pix % 56, hc = pix / 56;

  bf16x8 gA0, gA1, gB0, gB1;
  auto gatherIssue = [&](int ks) {
    int c0 = ks * 32 + jl * 8;
    int g0 = c0 / 37;
    int s0 = 3 - g0;
    int pa0 = pix + s0;           pa0 = pa0 < 0 ? 0 : (pa0 > HW - 1 ? HW - 1 : pa0);
    int pa1 = pix + s0 - 1;       pa1 = pa1 < 0 ? 0 : (pa1 > HW - 1 ? HW - 1 : pa1);
    int pb0 = pix + 56 * s0;      pb0 = pb0 < 0 ? 0 : (pb0 > HW - 1 ? HW - 1 : pb0);
    int pb1 = pix + 56 * (s0 - 1); pb1 = pb1 < 0 ? 0 : (pb1 > HW - 1 ? HW - 1 : pb1);
    gA0 = *(const bf16x8*)(tT + (nHW + pa0) * 256 + c0);
    gA1 = *(const bf16x8*)(tT + (nHW + pa1) * 256 + c0);
    gB0 = *(const bf16x8*)(tT + (nHW + pb0) * 256 + c0);
    gB1 = *(const bf16x8*)(tT + (nHW + pb1) * 256 + c0);
  };
  auto gatherWrite = [&](int par, int ks) {
    int c0 = ks * 32 + jl * 8;
    int g0 = c0 / 37;
    int s0 = 3 - g0;
    int js = (g0 + 1) * 37 - c0; if (js > 8) js = 8;
    bool a0 = (unsigned)(wc + s0) < 56u, a1 = (unsigned)(wc + s0 - 1) < 56u;
    bool b0 = (unsigned)(hc + s0) < 56u, b1 = (unsigned)(hc + s0 - 1) < 56u;
    bf16x8 va, vb;
#pragma unroll
    for (int j = 0; j < 8; ++j) {
      bool lo = j < js;
      va[j] = lo ? (a0 ? gA0[j] : (short)0) : (a1 ? gA1[j] : (short)0);
      vb[j] = lo ? (b0 ? gB0[j] : (short)0) : (b1 ? gB1[j] : (short)0);
    }
    if (t < 448) {
      *(bf16x8*)&lds[32768 + par * 3712 + (jl * 116 + p) * 8] = va;
      *(bf16x8*)&lds[40192 + par * 3712 + (jl * 116 + p) * 8] = vb;
    }
  };
  auto stageW = [&](int par, int ks) {
    int u0 = t; int r0 = u0 >> 2, sg0 = ((u0 & 3) - (r0 >> 1)) & 3;
    int u1 = t + 512; int r1 = u1 >> 2, sg1 = ((u1 & 3) - (r1 >> 1)) & 3;
    gload16(w21 + (size_t)r0 * 256 + ks * 32 + sg0 * 8, &lds[par * 8192 + wave * 512]);
    gload16(w21 + (size_t)r1 * 256 + ks * 32 + sg1 * 8, &lds[par * 8192 + 4096 + wave * 512]);
    gload16(w22 + (size_t)r0 * 256 + ks * 32 + sg0 * 8, &lds[16384 + par * 8192 + wave * 512]);
    gload16(w22 + (size_t)r1 * 256 + ks * 32 + sg1 * 8, &lds[16384 + par * 8192 + 4096 + wave * 512]);
  };

  int aU[2], bP[7];
#pragma unroll
  for (int os = 0; os < 2; ++os) { int row = wave * 32 + os * 16 + fr; aU[os] = (4 * row + ((fq + (row >> 1)) & 3)) * 8; }
#pragma unroll
  for (int ps = 0; ps < 7; ++ps) bP[ps] = (fq * 116 + ps * 16 + fr) * 8;

  f32x4 accA[2][7], accB[2][7];
#pragma unroll
  for (int a = 0; a < 2; ++a)
#pragma unroll
    for (int b = 0; b < 7; ++b) { accA[a][b] = (f32x4){0, 0, 0, 0}; accB[a][b] = (f32x4){0, 0, 0, 0}; }

  // prologue
  gatherIssue(0);
  stageW(0, 0);
  gatherWrite(0, 0);
  gatherIssue(1);
  __syncthreads();

#pragma unroll
  for (int k = 0; k < 8; ++k) {
    if (k < 7) stageW((k + 1) & 1, k + 1);
    bf16x8 afA[2], afB[2], bfA[7], bfB[7];
#pragma unroll
    for (int os = 0; os < 2; ++os) {
      afA[os] = *(const bf16x8*)&lds[(k & 1) * 8192 + aU[os]];
      afB[os] = *(const bf16x8*)&lds[16384 + (k & 1) * 8192 + aU[os]];
    }
#pragma unroll
    for (int ps = 0; ps < 7; ++ps) {
      bfA[ps] = *(const bf16x8*)&lds[32768 + (k & 1) * 3712 + bP[ps]];
      bfB[ps] = *(const bf16x8*)&lds[40192 + (k & 1) * 3712 + bP[ps]];
    }
#pragma unroll
    for (int os = 0; os < 2; ++os)
#pragma unroll
      for (int ps = 0; ps < 7; ++ps) {
        accA[os][ps] = __builtin_amdgcn_mfma_f32_16x16x32_bf16(afA[os], bfA[ps], accA[os][ps], 0, 0, 0);
        accB[os][ps] = __builtin_amdgcn_mfma_f32_16x16x32_bf16(afB[os], bfB[ps], accB[os][ps], 0, 0, 0);
      }
    if (k < 7) {
      gatherWrite((k + 1) & 1, k + 1);
      if (k < 6) gatherIssue(k + 2);
    }
    __syncthreads();
  }

  // epilogue: z + transpose store + stats
  char* tl = (char*)lds;
  float lsum = 0.f, lsq = 0.f;
#pragma unroll
  for (int os = 0; os < 2; ++os) {
    const int ob = wave * 32 + os * 16 + fq * 4;
    float4 a4 = *(const float4*)&b21[ob];
    float4 c4 = *(const float4*)&b22[ob];
    float ba[4] = {a4.x, a4.y, a4.z, a4.w};
    float bb[4] = {c4.x, c4.y, c4.z, c4.w};
#pragma unroll
    for (int ps = 0; ps < 7; ++ps) {
      const int pixL = ps * 16 + fr;
      u16x4 pk;
#pragma unroll
      for (int j = 0; j < 4; ++j) {
        float z = fgelu(accA[os][ps][j] + ba[j]) + fgelu(accB[os][ps][j] + bb[j]);
        lsum += z; lsq += z * z;
        pk[j] = (u16)f2bf(z);
      }
      const int qd = wave * 8 + os * 4 + fq;
      const int uq = qd ^ ((pixL & 15) << 2);
      *(u16x4*)(tl + pixL * 512 + uq * 8) = pk;
    }
  }
  __syncthreads();
#pragma unroll
  for (int r = 0; r < 7; ++r) {
    int idx = t + r * 512;
    int pixL = idx >> 5, oct = idx & 31;
    int up = (2 * oct) ^ ((pixL & 15) << 2);
    bf16x8 v = *(const bf16x8*)(tl + pixL * 512 + up * 8);
    *(bf16x8*)&zT[(nHW + hw0 + pixL) * 256 + oct * 8] = v;
  }
  __syncthreads();
  float* red = (float*)lds;
  red[t] = lsum; red[512 + t] = lsq;
  __syncthreads();
  for (int off = 256; off > 0; off >>= 1) {
    if (t < off) { red[t] += red[t + off]; red[512 + t] += red[512 + t + off]; }
    __syncthreads();
  }
  if (t == 0) { atomicAdd(&stats_out[n * 2], red[0]); atomicAdd(&stats_out[n * 2 + 1], red[512]); }
}

// ---- mlp3: out = x2 + fc2(fgelu(fc1(gn2(x2)))) fused; W direct global->reg, 9 barriers ----
__global__ __launch_bounds__(512, 2) void mlp3(
    const u16* __restrict__ x2T, const u16* __restrict__ wfc1, const u16* __restrict__ wfc2,
    const float* __restrict__ Sg, const float* __restrict__ Sb, const float* __restrict__ bias2,
    const float* __restrict__ stats_in, float* __restrict__ out_f32)
{
  // B1 (x2 tile, stride 113) [0, 28928); H (stride 116) [28928, 58624)  = 117 KB
  __shared__ __align__(16) u16 lds[58624];
  const int t = threadIdx.x;
  const int lane = t & 63, wave = t >> 6;
  const int fr = lane & 15, fq = lane >> 4;
  const int n = blockIdx.x / 28;
  const int hw0 = (blockIdx.x % 28) * 112;
  const size_t nHW = (size_t)n * HW;
  const int HOFF = 28928;

  // B1 prologue (reg-staged, padded stride 113 -> conflict-free reads)
#pragma unroll
  for (int i = 0; i < 7; ++i) {
    int u = wave * 448 + i * 64 + lane;
    int j = u / 112, p = u - j * 112;
    bf16x8 v = *(const bf16x8*)(x2T + (nHW + hw0 + p) * 256 + j * 8);
    *(bf16x8*)&lds[(j * 113 + p) * 8] = v;
  }

  float sm = stats_in[n * 2], sq = stats_in[n * 2 + 1];
  float mn = sm * (1.0f / NELF);
  float rstd = rsqrtf(sq * (1.0f / NELF) - mn * mn + EPS);
  float mr = mn * rstd;

  // W fragment bases: row = wave*32 + os*16 + fr, k-lane offset fq*8
  const int arow = wave * 32 + fr;
  const u16* w1base = wfc1 + (size_t)arow * 256 + fq * 8;   // + c*65536 + os*4096 + kk*32
  const u16* w2base = wfc2 + (size_t)arow * 1024 + fq * 8;  // + c*256 + os*16384 + kk*32

  f32x4 oacc[2][7];
#pragma unroll
  for (int a = 0; a < 2; ++a)
#pragma unroll
    for (int b = 0; b < 7; ++b) oacc[a][b] = (f32x4){0.f, 0.f, 0.f, 0.f};

  __syncthreads();   // B1 visible

  for (int c = 0; c < 4; ++c) {
    f32x4 hacc[2][7];
#pragma unroll
    for (int a = 0; a < 2; ++a)
#pragma unroll
      for (int b = 0; b < 7; ++b) hacc[a][b] = (f32x4){0.f, 0.f, 0.f, 0.f};

    // ---- fc1 phase: 8 ksteps, barrier-free (B1 read-only, W direct-global) ----
    const u16* w1c = w1base + (size_t)c * 65536;
#pragma unroll
    for (int kk = 0; kk < 8; ++kk) {
      bf16x8 a0 = *(const bf16x8*)(w1c + kk * 32);
      bf16x8 a1 = *(const bf16x8*)(w1c + 4096 + kk * 32);
      bf16x8 bfr[7];
#pragma unroll
      for (int ps = 0; ps < 7; ++ps)
        bfr[ps] = *(const bf16x8*)&lds[((kk * 4 + fq) * 113 + ps * 16 + fr) * 8];
#pragma unroll
      for (int ps = 0; ps < 7; ++ps) {
        hacc[0][ps] = __builtin_amdgcn_mfma_f32_16x16x32_bf16(a0, bfr[ps], hacc[0][ps], 0, 0, 0);
        hacc[1][ps] = __builtin_amdgcn_mfma_f32_16x16x32_bf16(a1, bfr[ps], hacc[1][ps], 0, 0, 0);
      }
    }

    // ---- H production: hid = fgelu(rstd*hacc + be) -> H plane ----
    {
      const int hcb = c * 256;
#pragma unroll
      for (int os = 0; os < 2; ++os) {
        const int hcl = wave * 32 + os * 16 + fq * 4;
        const int hc = hcb + hcl;
        float4 g4 = *(const float4*)&Sg[hc];
        float4 s4 = *(const float4*)&Sb[hc];
        float be[4] = {s4.x - mr * g4.x, s4.y - mr * g4.y, s4.z - mr * g4.z, s4.w - mr * g4.w};
        const int jH = hcl >> 3;
#pragma unroll
        for (int ps = 0; ps < 7; ++ps) {
          const int pixL = ps * 16 + fr;
          u16x4 pk;
#pragma unroll
          for (int j = 0; j < 4; ++j)
            pk[j] = (u16)f2bf(fgelu(fmaf(hacc[os][ps][j], rstd, be[j])));
          *(u16x4*)&lds[HOFF + (jH * 116 + pixL) * 8 + (fq & 1) * 4] = pk;
        }
      }
    }
    __syncthreads();   // H visible to all waves

    // ---- fc2 phase: 8 ksteps, barrier-free (H read-only, W direct-global) ----
    const u16* w2c = w2base + c * 256;
#pragma unroll
    for (int kk = 0; kk < 8; ++kk) {
      bf16x8 a0 = *(const bf16x8*)(w2c + kk * 32);
      bf16x8 a1 = *(const bf16x8*)(w2c + 16384 + kk * 32);
      bf16x8 bfr[7];
#pragma unroll
      for (int ps = 0; ps < 7; ++ps)
        bfr[ps] = *(const bf16x8*)&lds[HOFF + ((kk * 4 + fq) * 116 + ps * 16 + fr) * 8];
#pragma unroll
      for (int ps = 0; ps < 7; ++ps) {
        oacc[0][ps] = __builtin_amdgcn_mfma_f32_16x16x32_bf16(a0, bfr[ps], oacc[0][ps], 0, 0, 0);
        oacc[1][ps] = __builtin_amdgcn_mfma_f32_16x16x32_bf16(a1, bfr[ps], oacc[1][ps], 0, 0, 0);
      }
    }
    __syncthreads();   // H reads done before next chunk overwrites
  }

  // ---- epilogue: out = oacc + bias2 + x2 resid (from B1 plane) ----
#pragma unroll
  for (int os = 0; os < 2; ++os) {
    const int ob = wave * 32 + os * 16 + fq * 4;
    float4 b4 = *(const float4*)&bias2[ob];
    float bb[4] = {b4.x, b4.y, b4.z, b4.w};
#pragma unroll
    for (int ps = 0; ps < 7; ++ps) {
      const int pixL = ps * 16 + fr;
      u16x4 rv = *(const u16x4*)&lds[((ob >> 3) * 113 + pixL) * 8 + (ob & 4)];
#pragma unroll
      for (int j = 0; j < 4; ++j) {
        float v = oacc[os][ps][j] + bb[j] + b2f(rv[j]);
        out_f32[((size_t)n * 256 + ob + j) * HW + hw0 + pixL] = v;
      }
    }
  }
}

extern "C" void kernel_launch(void* const* d_in, const int* in_sizes, int n_in,
                              void* d_out, int out_size, void* d_ws, size_t ws_size,
                              hipStream_t stream) {
  const float* x     = (const float*)d_in[0];
  const float* n1_w  = (const float*)d_in[1];
  const float* n1_b  = (const float*)d_in[2];
  const float* c1_w  = (const float*)d_in[3];
  const float* c1_b  = (const float*)d_in[4];
  const float* an1_w = (const float*)d_in[5];
  const float* an1_b = (const float*)d_in[6];
  const float* c21_w = (const float*)d_in[7];
  const float* c21_b = (const float*)d_in[8];
  const float* c22_w = (const float*)d_in[9];
  const float* c22_b = (const float*)d_in[10];
  const float* an2_w = (const float*)d_in[11];
  const float* an2_b = (const float*)d_in[12];
  const float* c3_w  = (const float*)d_in[13];
  const float* c3_b  = (const float*)d_in[14];
  const float* n2_w  = (const float*)d_in[15];
  const float* n2_b  = (const float*)d_in[16];
  const float* fc1_w = (const float*)d_in[17];
  const float* fc1_b = (const float*)d_in[18];
  const float* fc2_w = (const float*)d_in[19];
  const float* fc2_b = (const float*)d_in[20];

  char* ws = (char*)d_ws;
  float* stats = (float*)ws;
  float* sums  = (float*)(ws + 1024);
  u16* wbuf = (u16*)(ws + 16384);
  u16* wb_c1g  = wbuf;
  u16* wb_c21  = wbuf + 65536;
  u16* wb_c22  = wbuf + 131072;
  u16* wb_c3g  = wbuf + 196608;
  u16* wb_fc1g = wbuf + 262144;
  u16* wb_fc2  = wbuf + 524288;
  const size_t AB = 25690112;
  char* A0 = ws + 1638400;
  u16* xT  = (u16*)(A0);
  u16* yT  = (u16*)(A0 + AB);
  u16* tT  = (u16*)(A0 + 2 * AB);
  u16* zT  = (u16*)(A0 + 3 * AB);
  u16* x2T = (u16*)(A0 + 4 * AB);
  float* out = (float*)d_out;

  hipMemsetAsync(stats, 0, 512, stream);
  wfold_kernel<<<768, 256, 0, stream>>>(c1_w, c21_w, c22_w, c3_w, fc1_w, fc2_w,
                                        n1_w, an2_w, n2_w, wbuf);
  rowsum_kernel<<<6, 256, 0, stream>>>(c1_w, c1_b, n1_w, n1_b, c3_w, c3_b, an2_w, an2_b,
                                       fc1_w, fc1_b, n2_w, n2_b, sums);
  t0_kernel<<<784, 256, 0, stream>>>(x, xT, stats + 0);
  // G1: y = conv1(gn1(x)) -> yT CL, stats(y)
  gemmW2<0><<<224, 512, 0, stream>>>(xT, wb_c1g, sums, sums + 256,
                                     stats + 0, stats + 32, nullptr, yT);
  // E2: t = fgelu(gn_as1(y)) -> tT CL
  e2_kernel<<<2048, 256, 0, stream>>>(yT, tT, an1_w, an1_b, stats + 32);
  // G2: z = fgelu(conv21(shift_w t)) + fgelu(conv22(shift_h t)) -> zT CL, stats(z)
  gemm_dual4<<<448, 512, 0, stream>>>(tT, wb_c21, wb_c22, c21_b, c22_b, stats + 64, zT);
  // G3: x2 = xT + conv3(gn_as2(z)) -> x2T CL, stats(x2)
  gemmW2<1><<<224, 512, 0, stream>>>(zT, wb_c3g, sums + 512, sums + 768,
                                     stats + 64, stats + 96, xT, x2T);
  // G4+G5 fused: out = x2 + fc2(fgelu(fc1(gn2(x2)))) -> d_out f32
  mlp3<<<448, 512, 0, stream>>>(x2T, wb_fc1g, wb_fc2, sums + 1024, sums + 2048,
                                fc2_b, stats + 96, out);
}